// Round 2
// baseline (265.082 us; speedup 1.0000x reference)
//
#include <hip/hip_runtime.h>
#include <math.h>

#define EMBED   64
#define HIDDEN  256
#define SEQ     200
#define SEQP    208          // padded to 13 s-tiles of 16
#define MT      13
#define VOCAB   100000

typedef _Float16 f16x8  __attribute__((ext_vector_type(8)));
typedef float    f32x4  __attribute__((ext_vector_type(4)));
typedef float    f32x2  __attribute__((ext_vector_type(2)));

// ---------------- ws layout ----------------
// [0   , 16K ) fragB8 : fp8 A-frags of 16*(W0+W2)  [tile 16][kc 2][lane 64] x 8B
// [16K , 48K ) fragW3 : f16 A-frags of 16*W3       [tile 16][kc 2][lane 64] x f16x8
// [48K , 80K ) fragDt : f16 A-frags of (W1-W2)^T   [tile 16][kc 2][lane 64] x f16x8
// [80K , 144K) fragB2 : f16 A-frags of mlp_w1      [tile 16][kc 4][lane 64] x f16x8
// [144K, 144K+6.4M) emb8: fp8(16*user_emb), row-major 64 B/vocab row (L3-resident)

// single setup kernel: weight frag packing (gid<10240) + emb8 conversion (rest)
__global__ void din_setup(const float* __restrict__ attn_w1,
                          const float* __restrict__ mlp_w1,
                          const float* __restrict__ user_emb,
                          uint2* __restrict__ fragB8,
                          _Float16* __restrict__ fragW3,
                          _Float16* __restrict__ fragDt,
                          _Float16* __restrict__ fragB2,
                          unsigned char* __restrict__ emb8,
                          int do_emb) {
  const int gid = blockIdx.x * 256 + threadIdx.x;   // [0, 110336)
  if (gid < 2048) {                                 // fragB8: fp8 16*(W0+W2)
    const int i = gid >> 7, rem = gid & 127, kc = rem >> 6, lane = rem & 63;
    const int n = i * 16 + (lane & 15);
    const int kb = kc * 32 + (lane >> 4) * 8;
    float v[8];
    #pragma unroll
    for (int j = 0; j < 8; ++j)
      v[j] = 16.0f * (attn_w1[(kb + j) * HIDDEN + n] + attn_w1[(128 + kb + j) * HIDDEN + n]);
    int lo = __builtin_amdgcn_cvt_pk_fp8_f32(v[0], v[1], 0, false);
    lo     = __builtin_amdgcn_cvt_pk_fp8_f32(v[2], v[3], lo, true);
    int hi = __builtin_amdgcn_cvt_pk_fp8_f32(v[4], v[5], 0, false);
    hi     = __builtin_amdgcn_cvt_pk_fp8_f32(v[6], v[7], hi, true);
    fragB8[gid] = uint2{(unsigned)lo, (unsigned)hi};
  } else if (gid < 4096) {                          // fragW3: f16 16*W3
    const int g = gid - 2048;
    const int i = g >> 7, rem = g & 127, kc = rem >> 6, lane = rem & 63;
    const int n = i * 16 + (lane & 15);
    const int kb = kc * 32 + (lane >> 4) * 8;
    #pragma unroll
    for (int j = 0; j < 8; ++j)
      fragW3[g * 8 + j] = (_Float16)(16.0f * attn_w1[(192 + kb + j) * HIDDEN + n]);
  } else if (gid < 6144) {                          // fragDt: f16 (W1-W2)^T A-frags
    const int g = gid - 4096;
    const int i = g >> 7, rem = g & 127, kc = rem >> 6, lane = rem & 63;
    const int n = i * 16 + (lane & 15);
    const int kb = kc * 32 + (lane >> 4) * 8;
    #pragma unroll
    for (int j = 0; j < 8; ++j)
      fragDt[g * 8 + j] = (_Float16)(attn_w1[(64 + kb + j) * HIDDEN + n]
                                   - attn_w1[(128 + kb + j) * HIDDEN + n]);
  } else if (gid < 10240) {                         // fragB2: mlp_w1 f16 A-frags
    const int g = gid - 6144;
    const int nt = g >> 8, kc = (g >> 6) & 3, lane = g & 63;
    const int n = nt * 16 + (lane & 15);
    const int kb = kc * 32 + (lane >> 4) * 8;
    #pragma unroll
    for (int j = 0; j < 8; ++j)
      fragB2[g * 8 + j] = (_Float16)mlp_w1[(kb + j) * HIDDEN + n];
  } else if (do_emb) {                              // emb8: fp8(16*user_emb), 8 elems/thread
    const int g = gid - 10240;                      // [0, 800000)
    if (g < VOCAB * EMBED / 8) {
      const int base = g * 8;
      const float4 x = *reinterpret_cast<const float4*>(&user_emb[base]);
      const float4 y = *reinterpret_cast<const float4*>(&user_emb[base + 4]);
      int lo = __builtin_amdgcn_cvt_pk_fp8_f32(16.f * x.x, 16.f * x.y, 0, false);
      lo     = __builtin_amdgcn_cvt_pk_fp8_f32(16.f * x.z, 16.f * x.w, lo, true);
      int hi = __builtin_amdgcn_cvt_pk_fp8_f32(16.f * y.x, 16.f * y.y, 0, false);
      hi     = __builtin_amdgcn_cvt_pk_fp8_f32(16.f * y.z, 16.f * y.w, hi, true);
      *reinterpret_cast<uint2*>(&emb8[base]) = uint2{(unsigned)lo, (unsigned)hi};
    }
  }
}

// ---------------- fused kernel: one block (512 thr, 8 waves) per TWO rows ----------------
// R13: 2 rows/block to amortize per-block overhead (9 barriers per 2 rows instead
// of per row; softmax fills all 8 waves: waves 0-3 row A, 4-7 row B; gather MLP
// doubles to 6.5 loads/thread). Phase 3 processes rows SEQUENTIALLY so per-wave
// live state (Aw 8 + cn 8 VGPR) stays at the R12 level - the 64-VGPR/(512,8)
// ceiling spills to scratch otherwise (R11: WRITE_SIZE 128KB -> 112MB).
// Logit partials stored f16 (summed f32 in softmax) to keep LDS at 37.2 KB ->
// 4 blocks/CU.
__global__ __launch_bounds__(512, 8)
void din_fused_kernel(const int* __restrict__ user_hist,
                      const int* __restrict__ target_item,
                      const float* __restrict__ user_emb,
                      const float* __restrict__ item_emb,
                      const float* __restrict__ attn_b1,
                      const float* __restrict__ attn_w2,
                      const float* __restrict__ mlp_b1,
                      const float* __restrict__ mlp_w2,
                      const float* __restrict__ mlp_b2,
                      const uint2* __restrict__ fragB8,
                      const _Float16* __restrict__ fragW3,
                      const _Float16* __restrict__ fragDt,
                      const _Float16* __restrict__ fragB2,
                      const unsigned char* __restrict__ emb8,   // may be null (ws too small)
                      float* __restrict__ out,
                      int batch)
{
  __shared__ __align__(16) uint2 Hf8[2][MT * 2 * 64];     // 26624 B, fp8(16h) B-frags
  __shared__ __align__(16) _Float16 lp16[2][8][SEQP];     // 6656 B, f16 logit partials
  __shared__ int   histL[2][SEQP];                        // 1664 B
  __shared__ float weights[2][SEQP];                      // 1664 B
  __shared__ __align__(16) _Float16 t16[2][EMBED];        // 256 B
  __shared__ __align__(16) _Float16 mi16[2][EMBED];       // 256 B
  __shared__ float red[16];                               // 64 B
  // total 37184 B -> 4 blocks/CU

  const int b    = blockIdx.x;
  const int tid  = threadIdx.x;
  const int lane = tid & 63;
  const int wave = tid >> 6;
  const int m    = lane & 15;
  const int quad = lane >> 4;
  const int bA   = 2 * b;
  const int bB   = (2 * b + 1 < batch) ? (2 * b + 1) : (2 * b);

  // ---- phase 0: target embeddings + hist staging (both rows) ----
  if (tid < 2 * EMBED) {
    const int r = tid >> 6, e = tid & 63;
    const int row = r ? bB : bA;
    t16[r][e] = (_Float16)item_emb[target_item[row] * EMBED + e];
  }
  if (tid < SEQP)
    histL[0][tid] = (tid < SEQ) ? user_hist[bA * SEQ + tid] : 0;
  if (tid >= 256 && tid < 256 + SEQP) {
    const int s = tid - 256;
    histL[1][s] = (s < SEQ) ? user_hist[bB * SEQ + s] : 0;
  }

  // static fp8 weight frag raw bits (row-independent) - preload before barrier
  uint2 w8r[2][2];
  #pragma unroll
  for (int i = 0; i < 2; ++i)
    #pragma unroll
    for (int c = 0; c < 2; ++c)
      w8r[i][c] = fragB8[((2 * wave + i) * 2 + c) * 64 + lane];
  __syncthreads();

  // ---- phase 1: gather h -> fp8 B-frag LDS, both rows (6.5 loads/thread) ----
  if (emb8) {
    for (int slot = tid; slot < 2 * MT * 2 * 64; slot += 512) {
      const int ln = slot & 63, kcomb = slot >> 6;       // 0..51
      const int r  = (kcomb >= MT * 2) ? 1 : 0;
      const int kk = kcomb - r * (MT * 2);
      const int st = kk >> 1, kc = kk & 1;
      const int s  = st * 16 + (ln & 15);
      const int kb = kc * 32 + (ln >> 4) * 8;
      uint2 pv = uint2{0u, 0u};
      if (s < SEQ)
        pv = *reinterpret_cast<const uint2*>(&emb8[histL[r][s] * EMBED + kb]);
      Hf8[r][kk * 64 + ln] = pv;
    }
  } else {
    for (int slot = tid; slot < 2 * MT * 2 * 64; slot += 512) {
      const int ln = slot & 63, kcomb = slot >> 6;
      const int r  = (kcomb >= MT * 2) ? 1 : 0;
      const int kk = kcomb - r * (MT * 2);
      const int st = kk >> 1, kc = kk & 1;
      const int s  = st * 16 + (ln & 15);
      const int kb = kc * 32 + (ln >> 4) * 8;
      uint2 pv = uint2{0u, 0u};
      if (s < SEQ) {
        const float4* src = reinterpret_cast<const float4*>(&user_emb[histL[r][s] * EMBED + kb]);
        const float4 x = src[0], y = src[1];
        int lo = __builtin_amdgcn_cvt_pk_fp8_f32(16.f * x.x, 16.f * x.y, 0, false);
        lo     = __builtin_amdgcn_cvt_pk_fp8_f32(16.f * x.z, 16.f * x.w, lo, true);
        int hi = __builtin_amdgcn_cvt_pk_fp8_f32(16.f * y.x, 16.f * y.y, 0, false);
        hi     = __builtin_amdgcn_cvt_pk_fp8_f32(16.f * y.z, 16.f * y.w, hi, true);
        pv = uint2{(unsigned)lo, (unsigned)hi};
      }
      Hf8[r][kk * 64 + ln] = pv;
    }
  }

  // ---- shared (row-independent) w2 scaling ----
  float w2n[2][4];
  #pragma unroll
  for (int i = 0; i < 2; ++i) {
    const float4 w2v = *reinterpret_cast<const float4*>(&attn_w2[(2 * wave + i) * 16 + quad * 4]);
    w2n[i][0] = w2v.x * (1.0f / 256.0f);
    w2n[i][1] = w2v.y * (1.0f / 256.0f);
    w2n[i][2] = w2v.z * (1.0f / 256.0f);
    w2n[i][3] = w2v.w * (1.0f / 256.0f);
  }

  // ---- phases 2+3, rows sequential: frag merge + c-fold, then fp8 K=64 GEMM ----
  #pragma unroll 1
  for (int r = 0; r < 2; ++r) {
    const f16x8 tv0 = *reinterpret_cast<const f16x8*>(&t16[r][quad * 8]);
    const f16x8 tv1 = *reinterpret_cast<const f16x8*>(&t16[r][32 + quad * 8]);

    // merged A-frags: fp8( 16*(W0+W2)[k][n] + 16*W3[k][n]*t[k] )
    long long Aw[2][2];
    #pragma unroll
    for (int i = 0; i < 2; ++i) {
      #pragma unroll
      for (int c = 0; c < 2; ++c) {
        const uint2 w8 = w8r[i][c];
        const f32x2 e0 = __builtin_amdgcn_cvt_pk_f32_fp8((int)w8.x, false);
        const f32x2 e1 = __builtin_amdgcn_cvt_pk_f32_fp8((int)w8.x, true);
        const f32x2 e2 = __builtin_amdgcn_cvt_pk_f32_fp8((int)w8.y, false);
        const f32x2 e3 = __builtin_amdgcn_cvt_pk_f32_fp8((int)w8.y, true);
        const f16x8 w3v = reinterpret_cast<const f16x8*>(fragW3)[((2 * wave + i) * 2 + c) * 64 + lane];
        const f16x8 p = w3v * (c ? tv1 : tv0);
        int lo = __builtin_amdgcn_cvt_pk_fp8_f32(e0.x + (float)p[0], e0.y + (float)p[1], 0, false);
        lo     = __builtin_amdgcn_cvt_pk_fp8_f32(e1.x + (float)p[2], e1.y + (float)p[3], lo, true);
        int hi = __builtin_amdgcn_cvt_pk_fp8_f32(e2.x + (float)p[4], e2.y + (float)p[5], 0, false);
        hi     = __builtin_amdgcn_cvt_pk_fp8_f32(e3.x + (float)p[6], e3.y + (float)p[7], hi, true);
        Aw[i][c] = __builtin_bit_cast(long long, uint2{(unsigned)lo, (unsigned)hi});
      }
    }

    // c-fold: c[n] = b1[n] + sum_k t[k] D[k][n]
    float cn[2][4];
    #pragma unroll
    for (int i = 0; i < 2; ++i) {
      const int tile = 2 * wave + i;
      const f16x8 d0 = reinterpret_cast<const f16x8*>(fragDt)[(tile * 2 + 0) * 64 + lane];
      const f16x8 d1 = reinterpret_cast<const f16x8*>(fragDt)[(tile * 2 + 1) * 64 + lane];
      f32x4 acc = {0.f, 0.f, 0.f, 0.f};
      acc = __builtin_amdgcn_mfma_f32_16x16x32_f16(d0, tv0, acc, 0, 0, 0);
      acc = __builtin_amdgcn_mfma_f32_16x16x32_f16(d1, tv1, acc, 0, 0, 0);
      const int nb = tile * 16 + quad * 4;
      const float4 b1v = *reinterpret_cast<const float4*>(&attn_b1[nb]);
      cn[i][0] = 256.0f * (b1v.x + acc[0]);
      cn[i][1] = 256.0f * (b1v.y + acc[1]);
      cn[i][2] = 256.0f * (b1v.z + acc[2]);
      cn[i][3] = 256.0f * (b1v.w + acc[3]);
    }

    // row A's frag work overlapped the gather drain; barrier once before Hf8 reads
    if (r == 0) __syncthreads();

    #pragma unroll 2
    for (int st = 0; st < MT; ++st) {
      const long long b0 = __builtin_bit_cast(long long, Hf8[r][(st * 2 + 0) * 64 + lane]);
      const long long b1 = __builtin_bit_cast(long long, Hf8[r][(st * 2 + 1) * 64 + lane]);
      float lg = 0.f;
      #pragma unroll
      for (int i = 0; i < 2; ++i) {
        f32x4 acc = {cn[i][0], cn[i][1], cn[i][2], cn[i][3]};
        acc = __builtin_amdgcn_mfma_f32_16x16x32_fp8_fp8(Aw[i][0], b0, acc, 0, 0, 0);
        acc = __builtin_amdgcn_mfma_f32_16x16x32_fp8_fp8(Aw[i][1], b1, acc, 0, 0, 0);
        #pragma unroll
        for (int q = 0; q < 4; ++q)
          lg += fmaxf(acc[q], 0.0f) * w2n[i][q];
      }
      lg += __shfl_xor(lg, 16, 64);
      lg += __shfl_xor(lg, 32, 64);
      if (lane < 16) lp16[r][wave][st * 16 + lane] = (_Float16)lg;
    }
  }
  __syncthreads();

  // ---- phase 4: softmax, all 8 waves (waves 0-3 row A, 4-7 row B) ----
  const int r4  = tid >> 8;          // row
  const int pos = tid & 255;
  float v = -INFINITY, e = 0.0f;
  if (pos < SEQ) {
    float s = 0.f;
    #pragma unroll
    for (int w = 0; w < 8; ++w) s += (float)lp16[r4][w][pos];
    v = s;
  }
  {
    float mx = v;
    #pragma unroll
    for (int off = 32; off; off >>= 1) mx = fmaxf(mx, __shfl_xor(mx, off, 64));
    if (lane == 0) red[wave] = mx;
  }
  __syncthreads();
  {
    const float mrow = fmaxf(fmaxf(red[4 * r4 + 0], red[4 * r4 + 1]),
                             fmaxf(red[4 * r4 + 2], red[4 * r4 + 3]));
    e = (pos < SEQ) ? expf(v - mrow) : 0.0f;
    float ssum = e;
    #pragma unroll
    for (int off = 32; off; off >>= 1) ssum += __shfl_xor(ssum, off, 64);
    if (lane == 0) red[8 + wave] = ssum;
  }
  __syncthreads();
  {
    const float tot = red[8 + 4 * r4 + 0] + red[8 + 4 * r4 + 1]
                    + red[8 + 4 * r4 + 2] + red[8 + 4 * r4 + 3];
    if (pos < SEQP) weights[r4][pos] = (pos < SEQ) ? e / tot : 0.0f;
  }
  __syncthreads();

  // ---- phase 5: weighted pooling; row = w>>2, kc = w&1, g2 = (w>>1)&1 ----
  {
    const int r = wave >> 2, kc = wave & 1, g2 = (wave >> 1) & 1;
    float pk[8];
    #pragma unroll
    for (int j = 0; j < 8; ++j) pk[j] = 0.f;
    #pragma unroll
    for (int st2 = 0; st2 < 7; ++st2) {
      const int st = g2 + 2 * st2;
      if (st < MT) {
        const float wt = weights[r][st * 16 + m];
        const uint2 hv = Hf8[r][(st * 2 + kc) * 64 + lane];
        const f32x2 f0 = __builtin_amdgcn_cvt_pk_f32_fp8((int)hv.x, false);
        const f32x2 f1 = __builtin_amdgcn_cvt_pk_f32_fp8((int)hv.x, true);
        const f32x2 f2 = __builtin_amdgcn_cvt_pk_f32_fp8((int)hv.y, false);
        const f32x2 f3 = __builtin_amdgcn_cvt_pk_f32_fp8((int)hv.y, true);
        pk[0] += wt * f0.x;  pk[1] += wt * f0.y;
        pk[2] += wt * f1.x;  pk[3] += wt * f1.y;
        pk[4] += wt * f2.x;  pk[5] += wt * f2.y;
        pk[6] += wt * f3.x;  pk[7] += wt * f3.y;
      }
    }
    #pragma unroll
    for (int j = 0; j < 8; ++j) {
      float p = pk[j];
      p += __shfl_xor(p, 1, 64);
      p += __shfl_xor(p, 2, 64);
      p += __shfl_xor(p, 4, 64);
      p += __shfl_xor(p, 8, 64);
      pk[j] = p;
    }
    if (m == 0) {
      float* ip = reinterpret_cast<float*>(&lp16[0][0][0]);   // lp16 reused: interest partials
      #pragma unroll
      for (int j = 0; j < 8; ++j)
        ip[((r << 1) + g2) * 64 + kc * 32 + quad * 8 + j] = pk[j];
    }
  }
  __syncthreads();
  if (tid < 2 * EMBED) {
    const int r = tid >> 6, e2 = tid & 63;
    const float* ip = reinterpret_cast<const float*>(&lp16[0][0][0]);
    mi16[r][e2] = (_Float16)((ip[(2 * r) * 64 + e2] + ip[(2 * r + 1) * 64 + e2]) * 0.0625f);
  }
  __syncthreads();

  // ---- phase 6: prediction head; row = w>>2, 4 n-tiles/wave ----
  {
    const int r = wave >> 2, sub = wave & 3;
    const f16x8 mb0 = *reinterpret_cast<const f16x8*>(&mi16[r][quad * 8]);
    const f16x8 mb1 = *reinterpret_cast<const f16x8*>(&mi16[r][32 + quad * 8]);
    const f16x8 tw0 = *reinterpret_cast<const f16x8*>(&t16[r][quad * 8]);
    const f16x8 tw1 = *reinterpret_cast<const f16x8*>(&t16[r][32 + quad * 8]);
    float z = 0.f;
    #pragma unroll
    for (int i = 0; i < 4; ++i) {
      const int tt = sub * 4 + i;
      const f16x8* B2 = reinterpret_cast<const f16x8*>(fragB2) + (tt * 4) * 64 + lane;
      const int nb = tt * 16 + quad * 4;
      const float4 bb = *reinterpret_cast<const float4*>(&mlp_b1[nb]);
      const float4 ww = *reinterpret_cast<const float4*>(&mlp_w2[nb]);
      f32x4 acc = {bb.x, bb.y, bb.z, bb.w};
      acc = __builtin_amdgcn_mfma_f32_16x16x32_f16(B2[0],   mb0, acc, 0, 0, 0);
      acc = __builtin_amdgcn_mfma_f32_16x16x32_f16(B2[64],  mb1, acc, 0, 0, 0);
      acc = __builtin_amdgcn_mfma_f32_16x16x32_f16(B2[128], tw0, acc, 0, 0, 0);
      acc = __builtin_amdgcn_mfma_f32_16x16x32_f16(B2[192], tw1, acc, 0, 0, 0);
      z += fmaxf(acc[0], 0.0f) * ww.x;
      z += fmaxf(acc[1], 0.0f) * ww.y;
      z += fmaxf(acc[2], 0.0f) * ww.z;
      z += fmaxf(acc[3], 0.0f) * ww.w;
    }
    z += __shfl_xor(z, 16, 64);
    z += __shfl_xor(z, 32, 64);
    if (lane == 0) red[wave] = z;
  }
  __syncthreads();
  if (tid == 0) {
    const float zz = red[0] + red[1] + red[2] + red[3] + mlp_b2[0];
    out[bA] = 1.0f / (1.0f + expf(-zz));
  } else if (tid == 256 && 2 * b + 1 < batch) {
    const float zz = red[4] + red[5] + red[6] + red[7] + mlp_b2[0];
    out[2 * b + 1] = 1.0f / (1.0f + expf(-zz));
  }
}

extern "C" void kernel_launch(void* const* d_in, const int* in_sizes, int n_in,
                              void* d_out, int out_size, void* d_ws, size_t ws_size,
                              hipStream_t stream) {
  const int*   user_hist   = (const int*)  d_in[0];
  const int*   target_item = (const int*)  d_in[1];
  const float* user_emb    = (const float*)d_in[2];
  const float* item_emb    = (const float*)d_in[3];
  const float* attn_w1     = (const float*)d_in[4];
  const float* attn_b1     = (const float*)d_in[5];
  const float* attn_w2     = (const float*)d_in[6];
  // d_in[7] = attn_b2: constant shift on logits -> cancels in softmax
  const float* mlp_w1      = (const float*)d_in[8];
  const float* mlp_b1      = (const float*)d_in[9];
  const float* mlp_w2      = (const float*)d_in[10];
  const float* mlp_b2      = (const float*)d_in[11];
  float* out = (float*)d_out;

  uint2*    fragB8 = (uint2*)d_ws;                           // 16 KB
  _Float16* fragW3 = (_Float16*)((char*)d_ws + 16384);       // 32 KB
  _Float16* fragDt = (_Float16*)((char*)d_ws + 49152);       // 32 KB
  _Float16* fragB2 = (_Float16*)((char*)d_ws + 81920);       // 64 KB
  const size_t emb8_off = 147456;
  const size_t emb8_bytes = (size_t)VOCAB * EMBED;           // 6.4 MB
  unsigned char* emb8 = nullptr;
  if (ws_size >= emb8_off + emb8_bytes)                      // ws_size is call-invariant: capture-safe
    emb8 = (unsigned char*)d_ws + emb8_off;

  // one setup launch: frag packing (gids 0..10239) + emb8 conversion (rest)
  const int setup_gids = 10240 + VOCAB * EMBED / 8;          // 110240
  din_setup<<<(setup_gids + 255) / 256, 256, 0, stream>>>(
      attn_w1, mlp_w1, user_emb, fragB8, fragW3, fragDt, fragB2,
      emb8 ? emb8 : (unsigned char*)d_ws, emb8 ? 1 : 0);

  const int batch = in_sizes[1];
  din_fused_kernel<<<(batch + 1) / 2, 512, 0, stream>>>(
      user_hist, target_item, user_emb, item_emb,
      attn_b1, attn_w2, mlp_b1, mlp_w2, mlp_b2,
      fragB8, fragW3, fragDt, fragB2, emb8, out, batch);
}

// Round 3
// 233.173 us; speedup vs baseline: 1.1368x; 1.1368x over previous
//
#include <hip/hip_runtime.h>
#include <math.h>

#define EMBED   64
#define HIDDEN  256
#define SEQ     200
#define SEQP    208          // padded to 13 s-tiles of 16
#define MT      13
#define VOCAB   100000

typedef _Float16 f16x8  __attribute__((ext_vector_type(8)));
typedef float    f32x4  __attribute__((ext_vector_type(4)));
typedef float    f32x2  __attribute__((ext_vector_type(2)));

// ---------------- ws layout ----------------
// [0   , 16K ) fragB8 : fp8 A-frags of 16*(W0+W2)  [tile 16][kc 2][lane 64] x 8B
// [16K , 48K ) fragW3 : f16 A-frags of 16*W3       [tile 16][kc 2][lane 64] x f16x8
// [48K , 80K ) fragDt : f16 A-frags of (W1-W2)^T   [tile 16][kc 2][lane 64] x f16x8
// [80K , 144K) fragB2 : f16 A-frags of mlp_w1      [tile 16][kc 4][lane 64] x f16x8
// [144K, 144K+6.4M) emb8: fp8(16*user_emb), row-major 64 B/vocab row (L3-resident)

// single setup kernel: weight frag packing (gid<10240) + emb8 conversion (rest)
__global__ void din_setup(const float* __restrict__ attn_w1,
                          const float* __restrict__ mlp_w1,
                          const float* __restrict__ user_emb,
                          uint2* __restrict__ fragB8,
                          _Float16* __restrict__ fragW3,
                          _Float16* __restrict__ fragDt,
                          _Float16* __restrict__ fragB2,
                          unsigned char* __restrict__ emb8,
                          int do_emb) {
  const int gid = blockIdx.x * 256 + threadIdx.x;   // [0, 110336)
  if (gid < 2048) {                                 // fragB8: fp8 16*(W0+W2)
    const int i = gid >> 7, rem = gid & 127, kc = rem >> 6, lane = rem & 63;
    const int n = i * 16 + (lane & 15);
    const int kb = kc * 32 + (lane >> 4) * 8;
    float v[8];
    #pragma unroll
    for (int j = 0; j < 8; ++j)
      v[j] = 16.0f * (attn_w1[(kb + j) * HIDDEN + n] + attn_w1[(128 + kb + j) * HIDDEN + n]);
    int lo = __builtin_amdgcn_cvt_pk_fp8_f32(v[0], v[1], 0, false);
    lo     = __builtin_amdgcn_cvt_pk_fp8_f32(v[2], v[3], lo, true);
    int hi = __builtin_amdgcn_cvt_pk_fp8_f32(v[4], v[5], 0, false);
    hi     = __builtin_amdgcn_cvt_pk_fp8_f32(v[6], v[7], hi, true);
    fragB8[gid] = uint2{(unsigned)lo, (unsigned)hi};
  } else if (gid < 4096) {                          // fragW3: f16 16*W3
    const int g = gid - 2048;
    const int i = g >> 7, rem = g & 127, kc = rem >> 6, lane = rem & 63;
    const int n = i * 16 + (lane & 15);
    const int kb = kc * 32 + (lane >> 4) * 8;
    #pragma unroll
    for (int j = 0; j < 8; ++j)
      fragW3[g * 8 + j] = (_Float16)(16.0f * attn_w1[(192 + kb + j) * HIDDEN + n]);
  } else if (gid < 6144) {                          // fragDt: f16 (W1-W2)^T A-frags
    const int g = gid - 4096;
    const int i = g >> 7, rem = g & 127, kc = rem >> 6, lane = rem & 63;
    const int n = i * 16 + (lane & 15);
    const int kb = kc * 32 + (lane >> 4) * 8;
    #pragma unroll
    for (int j = 0; j < 8; ++j)
      fragDt[g * 8 + j] = (_Float16)(attn_w1[(64 + kb + j) * HIDDEN + n]
                                   - attn_w1[(128 + kb + j) * HIDDEN + n]);
  } else if (gid < 10240) {                         // fragB2: mlp_w1 f16 A-frags
    const int g = gid - 6144;
    const int nt = g >> 8, kc = (g >> 6) & 3, lane = g & 63;
    const int n = nt * 16 + (lane & 15);
    const int kb = kc * 32 + (lane >> 4) * 8;
    #pragma unroll
    for (int j = 0; j < 8; ++j)
      fragB2[g * 8 + j] = (_Float16)mlp_w1[(kb + j) * HIDDEN + n];
  } else if (do_emb) {                              // emb8: fp8(16*user_emb), 8 elems/thread
    const int g = gid - 10240;                      // [0, 800000)
    if (g < VOCAB * EMBED / 8) {
      const int base = g * 8;
      const float4 x = *reinterpret_cast<const float4*>(&user_emb[base]);
      const float4 y = *reinterpret_cast<const float4*>(&user_emb[base + 4]);
      int lo = __builtin_amdgcn_cvt_pk_fp8_f32(16.f * x.x, 16.f * x.y, 0, false);
      lo     = __builtin_amdgcn_cvt_pk_fp8_f32(16.f * x.z, 16.f * x.w, lo, true);
      int hi = __builtin_amdgcn_cvt_pk_fp8_f32(16.f * y.x, 16.f * y.y, 0, false);
      hi     = __builtin_amdgcn_cvt_pk_fp8_f32(16.f * y.z, 16.f * y.w, hi, true);
      *reinterpret_cast<uint2*>(&emb8[base]) = uint2{(unsigned)lo, (unsigned)hi};
    }
  }
}

// ---------------- fused kernel: one block (512 thr, 8 waves) per TWO rows ----------------
// R13: 2 rows/block amortizes per-block overhead (shared gather barrier; softmax
// fills all 8 waves; 6.5-deep gather). R13 at launch_bounds(512,8) SPILLED:
// the 64-reg budget splits ~32 arch-VGPR / 32 AGPR, and the cross-row live set
// (w8r held across row A's GEMM) pushed a few dwords over -> per-st-iteration
// spill -> WRITE_SIZE 245 MB, dur 170 us.
// R14: launch_bounds(512,6) -> 3 blocks/CU (~84 VGPR budget). R12's measured
// occupancy was ~74% (~3 blocks/CU) anyway, so the concession is near-free and
// the spill clears. Pass criterion: WRITE_SIZE back to ~128 KB.
__global__ __launch_bounds__(512, 6)
void din_fused_kernel(const int* __restrict__ user_hist,
                      const int* __restrict__ target_item,
                      const float* __restrict__ user_emb,
                      const float* __restrict__ item_emb,
                      const float* __restrict__ attn_b1,
                      const float* __restrict__ attn_w2,
                      const float* __restrict__ mlp_b1,
                      const float* __restrict__ mlp_w2,
                      const float* __restrict__ mlp_b2,
                      const uint2* __restrict__ fragB8,
                      const _Float16* __restrict__ fragW3,
                      const _Float16* __restrict__ fragDt,
                      const _Float16* __restrict__ fragB2,
                      const unsigned char* __restrict__ emb8,   // may be null (ws too small)
                      float* __restrict__ out,
                      int batch)
{
  __shared__ __align__(16) uint2 Hf8[2][MT * 2 * 64];     // 26624 B, fp8(16h) B-frags
  __shared__ __align__(16) _Float16 lp16[2][8][SEQP];     // 6656 B, f16 logit partials
  __shared__ int   histL[2][SEQP];                        // 1664 B
  __shared__ float weights[2][SEQP];                      // 1664 B
  __shared__ __align__(16) _Float16 t16[2][EMBED];        // 256 B
  __shared__ __align__(16) _Float16 mi16[2][EMBED];       // 256 B
  __shared__ float red[16];                               // 64 B
  // total 37184 B -> 3 blocks/CU fits easily (111.6 KB)

  const int b    = blockIdx.x;
  const int tid  = threadIdx.x;
  const int lane = tid & 63;
  const int wave = tid >> 6;
  const int m    = lane & 15;
  const int quad = lane >> 4;
  const int bA   = 2 * b;
  const int bB   = (2 * b + 1 < batch) ? (2 * b + 1) : (2 * b);

  // ---- phase 0: target embeddings + hist staging (both rows) ----
  if (tid < 2 * EMBED) {
    const int r = tid >> 6, e = tid & 63;
    const int row = r ? bB : bA;
    t16[r][e] = (_Float16)item_emb[target_item[row] * EMBED + e];
  }
  if (tid < SEQP)
    histL[0][tid] = (tid < SEQ) ? user_hist[bA * SEQ + tid] : 0;
  if (tid >= 256 && tid < 256 + SEQP) {
    const int s = tid - 256;
    histL[1][s] = (s < SEQ) ? user_hist[bB * SEQ + s] : 0;
  }

  // static fp8 weight frag raw bits (row-independent) - preload before barrier
  uint2 w8r[2][2];
  #pragma unroll
  for (int i = 0; i < 2; ++i)
    #pragma unroll
    for (int c = 0; c < 2; ++c)
      w8r[i][c] = fragB8[((2 * wave + i) * 2 + c) * 64 + lane];
  __syncthreads();

  // ---- phase 1: gather h -> fp8 B-frag LDS, both rows (6.5 loads/thread) ----
  if (emb8) {
    for (int slot = tid; slot < 2 * MT * 2 * 64; slot += 512) {
      const int ln = slot & 63, kcomb = slot >> 6;       // 0..51
      const int r  = (kcomb >= MT * 2) ? 1 : 0;
      const int kk = kcomb - r * (MT * 2);
      const int st = kk >> 1, kc = kk & 1;
      const int s  = st * 16 + (ln & 15);
      const int kb = kc * 32 + (ln >> 4) * 8;
      uint2 pv = uint2{0u, 0u};
      if (s < SEQ)
        pv = *reinterpret_cast<const uint2*>(&emb8[histL[r][s] * EMBED + kb]);
      Hf8[r][kk * 64 + ln] = pv;
    }
  } else {
    for (int slot = tid; slot < 2 * MT * 2 * 64; slot += 512) {
      const int ln = slot & 63, kcomb = slot >> 6;
      const int r  = (kcomb >= MT * 2) ? 1 : 0;
      const int kk = kcomb - r * (MT * 2);
      const int st = kk >> 1, kc = kk & 1;
      const int s  = st * 16 + (ln & 15);
      const int kb = kc * 32 + (ln >> 4) * 8;
      uint2 pv = uint2{0u, 0u};
      if (s < SEQ) {
        const float4* src = reinterpret_cast<const float4*>(&user_emb[histL[r][s] * EMBED + kb]);
        const float4 x = src[0], y = src[1];
        int lo = __builtin_amdgcn_cvt_pk_fp8_f32(16.f * x.x, 16.f * x.y, 0, false);
        lo     = __builtin_amdgcn_cvt_pk_fp8_f32(16.f * x.z, 16.f * x.w, lo, true);
        int hi = __builtin_amdgcn_cvt_pk_fp8_f32(16.f * y.x, 16.f * y.y, 0, false);
        hi     = __builtin_amdgcn_cvt_pk_fp8_f32(16.f * y.z, 16.f * y.w, hi, true);
        pv = uint2{(unsigned)lo, (unsigned)hi};
      }
      Hf8[r][kk * 64 + ln] = pv;
    }
  }

  // ---- shared (row-independent) w2 scaling ----
  float w2n[2][4];
  #pragma unroll
  for (int i = 0; i < 2; ++i) {
    const float4 w2v = *reinterpret_cast<const float4*>(&attn_w2[(2 * wave + i) * 16 + quad * 4]);
    w2n[i][0] = w2v.x * (1.0f / 256.0f);
    w2n[i][1] = w2v.y * (1.0f / 256.0f);
    w2n[i][2] = w2v.z * (1.0f / 256.0f);
    w2n[i][3] = w2v.w * (1.0f / 256.0f);
  }

  // ---- phases 2+3, rows sequential: frag merge + c-fold, then fp8 K=64 GEMM ----
  #pragma unroll 1
  for (int r = 0; r < 2; ++r) {
    const f16x8 tv0 = *reinterpret_cast<const f16x8*>(&t16[r][quad * 8]);
    const f16x8 tv1 = *reinterpret_cast<const f16x8*>(&t16[r][32 + quad * 8]);

    // merged A-frags: fp8( 16*(W0+W2)[k][n] + 16*W3[k][n]*t[k] )
    long long Aw[2][2];
    #pragma unroll
    for (int i = 0; i < 2; ++i) {
      #pragma unroll
      for (int c = 0; c < 2; ++c) {
        const uint2 w8 = w8r[i][c];
        const f32x2 e0 = __builtin_amdgcn_cvt_pk_f32_fp8((int)w8.x, false);
        const f32x2 e1 = __builtin_amdgcn_cvt_pk_f32_fp8((int)w8.x, true);
        const f32x2 e2 = __builtin_amdgcn_cvt_pk_f32_fp8((int)w8.y, false);
        const f32x2 e3 = __builtin_amdgcn_cvt_pk_f32_fp8((int)w8.y, true);
        const f16x8 w3v = reinterpret_cast<const f16x8*>(fragW3)[((2 * wave + i) * 2 + c) * 64 + lane];
        const f16x8 p = w3v * (c ? tv1 : tv0);
        int lo = __builtin_amdgcn_cvt_pk_fp8_f32(e0.x + (float)p[0], e0.y + (float)p[1], 0, false);
        lo     = __builtin_amdgcn_cvt_pk_fp8_f32(e1.x + (float)p[2], e1.y + (float)p[3], lo, true);
        int hi = __builtin_amdgcn_cvt_pk_fp8_f32(e2.x + (float)p[4], e2.y + (float)p[5], 0, false);
        hi     = __builtin_amdgcn_cvt_pk_fp8_f32(e3.x + (float)p[6], e3.y + (float)p[7], hi, true);
        Aw[i][c] = __builtin_bit_cast(long long, uint2{(unsigned)lo, (unsigned)hi});
      }
    }

    // c-fold: c[n] = b1[n] + sum_k t[k] D[k][n]
    float cn[2][4];
    #pragma unroll
    for (int i = 0; i < 2; ++i) {
      const int tile = 2 * wave + i;
      const f16x8 d0 = reinterpret_cast<const f16x8*>(fragDt)[(tile * 2 + 0) * 64 + lane];
      const f16x8 d1 = reinterpret_cast<const f16x8*>(fragDt)[(tile * 2 + 1) * 64 + lane];
      f32x4 acc = {0.f, 0.f, 0.f, 0.f};
      acc = __builtin_amdgcn_mfma_f32_16x16x32_f16(d0, tv0, acc, 0, 0, 0);
      acc = __builtin_amdgcn_mfma_f32_16x16x32_f16(d1, tv1, acc, 0, 0, 0);
      const int nb = tile * 16 + quad * 4;
      const float4 b1v = *reinterpret_cast<const float4*>(&attn_b1[nb]);
      cn[i][0] = 256.0f * (b1v.x + acc[0]);
      cn[i][1] = 256.0f * (b1v.y + acc[1]);
      cn[i][2] = 256.0f * (b1v.z + acc[2]);
      cn[i][3] = 256.0f * (b1v.w + acc[3]);
    }

    // row A's frag work overlapped the gather drain; barrier once before Hf8 reads
    if (r == 0) __syncthreads();

    #pragma unroll 2
    for (int st = 0; st < MT; ++st) {
      const long long b0 = __builtin_bit_cast(long long, Hf8[r][(st * 2 + 0) * 64 + lane]);
      const long long b1 = __builtin_bit_cast(long long, Hf8[r][(st * 2 + 1) * 64 + lane]);
      float lg = 0.f;
      #pragma unroll
      for (int i = 0; i < 2; ++i) {
        f32x4 acc = {cn[i][0], cn[i][1], cn[i][2], cn[i][3]};
        acc = __builtin_amdgcn_mfma_f32_16x16x32_fp8_fp8(Aw[i][0], b0, acc, 0, 0, 0);
        acc = __builtin_amdgcn_mfma_f32_16x16x32_fp8_fp8(Aw[i][1], b1, acc, 0, 0, 0);
        #pragma unroll
        for (int q = 0; q < 4; ++q)
          lg += fmaxf(acc[q], 0.0f) * w2n[i][q];
      }
      lg += __shfl_xor(lg, 16, 64);
      lg += __shfl_xor(lg, 32, 64);
      if (lane < 16) lp16[r][wave][st * 16 + lane] = (_Float16)lg;
    }
  }
  __syncthreads();

  // ---- phase 4: softmax, all 8 waves (waves 0-3 row A, 4-7 row B) ----
  const int r4  = tid >> 8;          // row
  const int pos = tid & 255;
  float v = -INFINITY, e = 0.0f;
  if (pos < SEQ) {
    float s = 0.f;
    #pragma unroll
    for (int w = 0; w < 8; ++w) s += (float)lp16[r4][w][pos];
    v = s;
  }
  {
    float mx = v;
    #pragma unroll
    for (int off = 32; off; off >>= 1) mx = fmaxf(mx, __shfl_xor(mx, off, 64));
    if (lane == 0) red[wave] = mx;
  }
  __syncthreads();
  {
    const float mrow = fmaxf(fmaxf(red[4 * r4 + 0], red[4 * r4 + 1]),
                             fmaxf(red[4 * r4 + 2], red[4 * r4 + 3]));
    e = (pos < SEQ) ? expf(v - mrow) : 0.0f;
    float ssum = e;
    #pragma unroll
    for (int off = 32; off; off >>= 1) ssum += __shfl_xor(ssum, off, 64);
    if (lane == 0) red[8 + wave] = ssum;
  }
  __syncthreads();
  {
    const float tot = red[8 + 4 * r4 + 0] + red[8 + 4 * r4 + 1]
                    + red[8 + 4 * r4 + 2] + red[8 + 4 * r4 + 3];
    if (pos < SEQP) weights[r4][pos] = (pos < SEQ) ? e / tot : 0.0f;
  }
  __syncthreads();

  // ---- phase 5: weighted pooling; row = w>>2, kc = w&1, g2 = (w>>1)&1 ----
  {
    const int r = wave >> 2, kc = wave & 1, g2 = (wave >> 1) & 1;
    float pk[8];
    #pragma unroll
    for (int j = 0; j < 8; ++j) pk[j] = 0.f;
    #pragma unroll
    for (int st2 = 0; st2 < 7; ++st2) {
      const int st = g2 + 2 * st2;
      if (st < MT) {
        const float wt = weights[r][st * 16 + m];
        const uint2 hv = Hf8[r][(st * 2 + kc) * 64 + lane];
        const f32x2 f0 = __builtin_amdgcn_cvt_pk_f32_fp8((int)hv.x, false);
        const f32x2 f1 = __builtin_amdgcn_cvt_pk_f32_fp8((int)hv.x, true);
        const f32x2 f2 = __builtin_amdgcn_cvt_pk_f32_fp8((int)hv.y, false);
        const f32x2 f3 = __builtin_amdgcn_cvt_pk_f32_fp8((int)hv.y, true);
        pk[0] += wt * f0.x;  pk[1] += wt * f0.y;
        pk[2] += wt * f1.x;  pk[3] += wt * f1.y;
        pk[4] += wt * f2.x;  pk[5] += wt * f2.y;
        pk[6] += wt * f3.x;  pk[7] += wt * f3.y;
      }
    }
    #pragma unroll
    for (int j = 0; j < 8; ++j) {
      float p = pk[j];
      p += __shfl_xor(p, 1, 64);
      p += __shfl_xor(p, 2, 64);
      p += __shfl_xor(p, 4, 64);
      p += __shfl_xor(p, 8, 64);
      pk[j] = p;
    }
    if (m == 0) {
      float* ip = reinterpret_cast<float*>(&lp16[0][0][0]);   // lp16 reused: interest partials
      #pragma unroll
      for (int j = 0; j < 8; ++j)
        ip[((r << 1) + g2) * 64 + kc * 32 + quad * 8 + j] = pk[j];
    }
  }
  __syncthreads();
  if (tid < 2 * EMBED) {
    const int r = tid >> 6, e2 = tid & 63;
    const float* ip = reinterpret_cast<const float*>(&lp16[0][0][0]);
    mi16[r][e2] = (_Float16)((ip[(2 * r) * 64 + e2] + ip[(2 * r + 1) * 64 + e2]) * 0.0625f);
  }
  __syncthreads();

  // ---- phase 6: prediction head; row = w>>2, 4 n-tiles/wave ----
  {
    const int r = wave >> 2, sub = wave & 3;
    const f16x8 mb0 = *reinterpret_cast<const f16x8*>(&mi16[r][quad * 8]);
    const f16x8 mb1 = *reinterpret_cast<const f16x8*>(&mi16[r][32 + quad * 8]);
    const f16x8 tw0 = *reinterpret_cast<const f16x8*>(&t16[r][quad * 8]);
    const f16x8 tw1 = *reinterpret_cast<const f16x8*>(&t16[r][32 + quad * 8]);
    float z = 0.f;
    #pragma unroll
    for (int i = 0; i < 4; ++i) {
      const int tt = sub * 4 + i;
      const f16x8* B2 = reinterpret_cast<const f16x8*>(fragB2) + (tt * 4) * 64 + lane;
      const int nb = tt * 16 + quad * 4;
      const float4 bb = *reinterpret_cast<const float4*>(&mlp_b1[nb]);
      const float4 ww = *reinterpret_cast<const float4*>(&mlp_w2[nb]);
      f32x4 acc = {bb.x, bb.y, bb.z, bb.w};
      acc = __builtin_amdgcn_mfma_f32_16x16x32_f16(B2[0],   mb0, acc, 0, 0, 0);
      acc = __builtin_amdgcn_mfma_f32_16x16x32_f16(B2[64],  mb1, acc, 0, 0, 0);
      acc = __builtin_amdgcn_mfma_f32_16x16x32_f16(B2[128], tw0, acc, 0, 0, 0);
      acc = __builtin_amdgcn_mfma_f32_16x16x32_f16(B2[192], tw1, acc, 0, 0, 0);
      z += fmaxf(acc[0], 0.0f) * ww.x;
      z += fmaxf(acc[1], 0.0f) * ww.y;
      z += fmaxf(acc[2], 0.0f) * ww.z;
      z += fmaxf(acc[3], 0.0f) * ww.w;
    }
    z += __shfl_xor(z, 16, 64);
    z += __shfl_xor(z, 32, 64);
    if (lane == 0) red[wave] = z;
  }
  __syncthreads();
  if (tid == 0) {
    const float zz = red[0] + red[1] + red[2] + red[3] + mlp_b2[0];
    out[bA] = 1.0f / (1.0f + expf(-zz));
  } else if (tid == 256 && 2 * b + 1 < batch) {
    const float zz = red[4] + red[5] + red[6] + red[7] + mlp_b2[0];
    out[2 * b + 1] = 1.0f / (1.0f + expf(-zz));
  }
}

extern "C" void kernel_launch(void* const* d_in, const int* in_sizes, int n_in,
                              void* d_out, int out_size, void* d_ws, size_t ws_size,
                              hipStream_t stream) {
  const int*   user_hist   = (const int*)  d_in[0];
  const int*   target_item = (const int*)  d_in[1];
  const float* user_emb    = (const float*)d_in[2];
  const float* item_emb    = (const float*)d_in[3];
  const float* attn_w1     = (const float*)d_in[4];
  const float* attn_b1     = (const float*)d_in[5];
  const float* attn_w2     = (const float*)d_in[6];
  // d_in[7] = attn_b2: constant shift on logits -> cancels in softmax
  const float* mlp_w1      = (const float*)d_in[8];
  const float* mlp_b1      = (const float*)d_in[9];
  const float* mlp_w2      = (const float*)d_in[10];
  const float* mlp_b2      = (const float*)d_in[11];
  float* out = (float*)d_out;

  uint2*    fragB8 = (uint2*)d_ws;                           // 16 KB
  _Float16* fragW3 = (_Float16*)((char*)d_ws + 16384);       // 32 KB
  _Float16* fragDt = (_Float16*)((char*)d_ws + 49152);       // 32 KB
  _Float16* fragB2 = (_Float16*)((char*)d_ws + 81920);       // 64 KB
  const size_t emb8_off = 147456;
  const size_t emb8_bytes = (size_t)VOCAB * EMBED;           // 6.4 MB
  unsigned char* emb8 = nullptr;
  if (ws_size >= emb8_off + emb8_bytes)                      // ws_size is call-invariant: capture-safe
    emb8 = (unsigned char*)d_ws + emb8_off;

  // one setup launch: frag packing (gids 0..10239) + emb8 conversion (rest)
  const int setup_gids = 10240 + VOCAB * EMBED / 8;          // 110240
  din_setup<<<(setup_gids + 255) / 256, 256, 0, stream>>>(
      attn_w1, mlp_w1, user_emb, fragB8, fragW3, fragDt, fragB2,
      emb8 ? emb8 : (unsigned char*)d_ws, emb8 ? 1 : 0);

  const int batch = in_sizes[1];
  din_fused_kernel<<<(batch + 1) / 2, 512, 0, stream>>>(
      user_hist, target_item, user_emb, item_emb,
      attn_b1, attn_w2, mlp_b1, mlp_w2, mlp_b2,
      fragB8, fragW3, fragDt, fragB2, emb8, out, batch);
}

// Round 4
// 169.004 us; speedup vs baseline: 1.5685x; 1.3797x over previous
//
#include <hip/hip_runtime.h>
#include <math.h>

#define EMBED   64
#define HIDDEN  256
#define SEQ     200
#define SEQP    208          // padded to 13 s-tiles of 16
#define MT      13
#define VOCAB   100000

typedef _Float16 f16x8  __attribute__((ext_vector_type(8)));
typedef float    f32x4  __attribute__((ext_vector_type(4)));
typedef float    f32x2  __attribute__((ext_vector_type(2)));

// ---------------- ws layout ----------------
// [0   , 16K ) fragB8 : fp8 A-frags of 16*(W0+W2)  [tile 16][kc 2][lane 64] x 8B
// [16K , 48K ) fragW3 : f16 A-frags of 16*W3       [tile 16][kc 2][lane 64] x f16x8
// [48K , 80K ) fragDt : f16 A-frags of (W1-W2)^T   [tile 16][kc 2][lane 64] x f16x8
// [80K , 144K) fragB2 : f16 A-frags of mlp_w1      [tile 16][kc 4][lane 64] x f16x8
// [144K, 144K+6.4M) emb8: fp8(16*user_emb), row-major 64 B/vocab row (L3-resident)

// single setup kernel: weight frag packing (gid<10240) + emb8 conversion (rest)
__global__ void din_setup(const float* __restrict__ attn_w1,
                          const float* __restrict__ mlp_w1,
                          const float* __restrict__ user_emb,
                          uint2* __restrict__ fragB8,
                          _Float16* __restrict__ fragW3,
                          _Float16* __restrict__ fragDt,
                          _Float16* __restrict__ fragB2,
                          unsigned char* __restrict__ emb8,
                          int do_emb) {
  const int gid = blockIdx.x * 256 + threadIdx.x;   // [0, 110336)
  if (gid < 2048) {                                 // fragB8: fp8 16*(W0+W2)
    const int i = gid >> 7, rem = gid & 127, kc = rem >> 6, lane = rem & 63;
    const int n = i * 16 + (lane & 15);
    const int kb = kc * 32 + (lane >> 4) * 8;
    float v[8];
    #pragma unroll
    for (int j = 0; j < 8; ++j)
      v[j] = 16.0f * (attn_w1[(kb + j) * HIDDEN + n] + attn_w1[(128 + kb + j) * HIDDEN + n]);
    int lo = __builtin_amdgcn_cvt_pk_fp8_f32(v[0], v[1], 0, false);
    lo     = __builtin_amdgcn_cvt_pk_fp8_f32(v[2], v[3], lo, true);
    int hi = __builtin_amdgcn_cvt_pk_fp8_f32(v[4], v[5], 0, false);
    hi     = __builtin_amdgcn_cvt_pk_fp8_f32(v[6], v[7], hi, true);
    fragB8[gid] = uint2{(unsigned)lo, (unsigned)hi};
  } else if (gid < 4096) {                          // fragW3: f16 16*W3
    const int g = gid - 2048;
    const int i = g >> 7, rem = g & 127, kc = rem >> 6, lane = rem & 63;
    const int n = i * 16 + (lane & 15);
    const int kb = kc * 32 + (lane >> 4) * 8;
    #pragma unroll
    for (int j = 0; j < 8; ++j)
      fragW3[g * 8 + j] = (_Float16)(16.0f * attn_w1[(192 + kb + j) * HIDDEN + n]);
  } else if (gid < 6144) {                          // fragDt: f16 (W1-W2)^T A-frags
    const int g = gid - 4096;
    const int i = g >> 7, rem = g & 127, kc = rem >> 6, lane = rem & 63;
    const int n = i * 16 + (lane & 15);
    const int kb = kc * 32 + (lane >> 4) * 8;
    #pragma unroll
    for (int j = 0; j < 8; ++j)
      fragDt[g * 8 + j] = (_Float16)(attn_w1[(64 + kb + j) * HIDDEN + n]
                                   - attn_w1[(128 + kb + j) * HIDDEN + n]);
  } else if (gid < 10240) {                         // fragB2: mlp_w1 f16 A-frags
    const int g = gid - 6144;
    const int nt = g >> 8, kc = (g >> 6) & 3, lane = g & 63;
    const int n = nt * 16 + (lane & 15);
    const int kb = kc * 32 + (lane >> 4) * 8;
    #pragma unroll
    for (int j = 0; j < 8; ++j)
      fragB2[g * 8 + j] = (_Float16)mlp_w1[(kb + j) * HIDDEN + n];
  } else if (do_emb) {                              // emb8: fp8(16*user_emb), 8 elems/thread
    const int g = gid - 10240;                      // [0, 800000)
    if (g < VOCAB * EMBED / 8) {
      const int base = g * 8;
      const float4 x = *reinterpret_cast<const float4*>(&user_emb[base]);
      const float4 y = *reinterpret_cast<const float4*>(&user_emb[base + 4]);
      int lo = __builtin_amdgcn_cvt_pk_fp8_f32(16.f * x.x, 16.f * x.y, 0, false);
      lo     = __builtin_amdgcn_cvt_pk_fp8_f32(16.f * x.z, 16.f * x.w, lo, true);
      int hi = __builtin_amdgcn_cvt_pk_fp8_f32(16.f * y.x, 16.f * y.y, 0, false);
      hi     = __builtin_amdgcn_cvt_pk_fp8_f32(16.f * y.z, 16.f * y.w, hi, true);
      *reinterpret_cast<uint2*>(&emb8[base]) = uint2{(unsigned)lo, (unsigned)hi};
    }
  }
}

// ---------------- fused kernel: one block (256 thr, 4 waves) per row ----------------
// R15: R12's proven single-row dataflow re-tiled to 256-thread blocks.
// Rationale: R12 (512 thr) had no saturated pipe (Mfma 18 / VALU 59 / occ 74) ->
// barrier+latency serialization. 256-thr blocks double resident blocks/CU
// (6 at launch_bounds(256,6), same 24 waves/CU) and halve barrier-group width
// and softmax idle lanes.
// Each wave owns 4 n-tiles processed as 2 SEQUENTIAL PAIRS with the A-frag
// merge recomputed per pair, so the GEMM live set stays R12-sized (~40 regs).
// Logit accumulation across pairs goes through LDS f32, NOT registers.
// LESSON (R13/R14): cross-row/cross-pair register state spills at tight
// launch_bounds (WRITE_SIZE 128KB -> 180+MB). Keep per-phase live sets small;
// pass criterion for this round: WRITE_SIZE ~128 KB.
__global__ __launch_bounds__(256, 6)
void din_fused_kernel(const int* __restrict__ user_hist,
                      const int* __restrict__ target_item,
                      const float* __restrict__ user_emb,
                      const float* __restrict__ item_emb,
                      const float* __restrict__ attn_b1,
                      const float* __restrict__ attn_w2,
                      const float* __restrict__ mlp_b1,
                      const float* __restrict__ mlp_w2,
                      const float* __restrict__ mlp_b2,
                      const uint2* __restrict__ fragB8,
                      const _Float16* __restrict__ fragW3,
                      const _Float16* __restrict__ fragDt,
                      const _Float16* __restrict__ fragB2,
                      const unsigned char* __restrict__ emb8,   // may be null (ws too small)
                      float* __restrict__ out)
{
  __shared__ __align__(16) uint2 Hf8[MT * 2 * 64];    // 13312 B, fp8(16h) B-frags
  __shared__ float lpf[4][SEQP];                      // 3328 B, f32 logit partials (reused as ip)
  __shared__ int   histL[SEQP];                       // 832
  __shared__ float weights[SEQP];                     // 832
  __shared__ __align__(16) _Float16 t16[EMBED];       // 128
  __shared__ __align__(16) _Float16 mi16[EMBED];      // 128
  __shared__ float red[8];                            // 32
  // total ~18.6 KB -> 6 blocks/CU = 112 KB

  const int b    = blockIdx.x;
  const int tid  = threadIdx.x;
  const int lane = tid & 63;
  const int wave = tid >> 6;
  const int m    = lane & 15;
  const int quad = lane >> 4;

  // ---- phase 0: target embedding + hist staging ----
  if (tid < EMBED) t16[tid] = (_Float16)item_emb[target_item[b] * EMBED + tid];
  if (tid < SEQP) histL[tid] = (tid < SEQ) ? user_hist[b * SEQ + tid] : 0;
  __syncthreads();

  // ---- phase 1: gather h -> fp8 B-frag LDS (6.5 loads/thread) ----
  if (emb8) {
    for (int slot = tid; slot < MT * 2 * 64; slot += 256) {
      const int ln = slot & 63, kcomb = slot >> 6;
      const int st = kcomb >> 1, kc = kcomb & 1;
      const int s = st * 16 + (ln & 15);
      const int kb = kc * 32 + (ln >> 4) * 8;
      uint2 pv = uint2{0u, 0u};
      if (s < SEQ)
        pv = *reinterpret_cast<const uint2*>(&emb8[histL[s] * EMBED + kb]);
      Hf8[slot] = pv;
    }
  } else {
    for (int slot = tid; slot < MT * 2 * 64; slot += 256) {
      const int ln = slot & 63, kcomb = slot >> 6;
      const int st = kcomb >> 1, kc = kcomb & 1;
      const int s = st * 16 + (ln & 15);
      const int kb = kc * 32 + (ln >> 4) * 8;
      uint2 pv = uint2{0u, 0u};
      if (s < SEQ) {
        const float4* src = reinterpret_cast<const float4*>(&user_emb[histL[s] * EMBED + kb]);
        const float4 x = src[0], y = src[1];
        int lo = __builtin_amdgcn_cvt_pk_fp8_f32(16.f * x.x, 16.f * x.y, 0, false);
        lo     = __builtin_amdgcn_cvt_pk_fp8_f32(16.f * x.z, 16.f * x.w, lo, true);
        int hi = __builtin_amdgcn_cvt_pk_fp8_f32(16.f * y.x, 16.f * y.y, 0, false);
        hi     = __builtin_amdgcn_cvt_pk_fp8_f32(16.f * y.z, 16.f * y.w, hi, true);
        pv = uint2{(unsigned)lo, (unsigned)hi};
      }
      Hf8[slot] = pv;
    }
  }

  // broadcast target fragments (valid after phase-0 barrier)
  const f16x8 tv0 = *reinterpret_cast<const f16x8*>(&t16[quad * 8]);
  const f16x8 tv1 = *reinterpret_cast<const f16x8*>(&t16[32 + quad * 8]);

  // ---- phases 2+3: two pairs of n-tiles per wave; merge recomputed per pair ----
  // pair 0's merge overlaps the gather VMEM drain (touches only t16 + global frags)
  #pragma unroll 1
  for (int p = 0; p < 2; ++p) {
    long long Aw[2][2];
    float cn[2][4], w2n[2][4];
    #pragma unroll
    for (int i = 0; i < 2; ++i) {
      const int tile = wave * 4 + p * 2 + i;
      // merged A-frags: fp8( 16*(W0+W2)[k][n] + 16*W3[k][n]*t[k] )
      #pragma unroll
      for (int c = 0; c < 2; ++c) {
        const uint2 w8 = fragB8[(tile * 2 + c) * 64 + lane];
        const f32x2 e0 = __builtin_amdgcn_cvt_pk_f32_fp8((int)w8.x, false);
        const f32x2 e1 = __builtin_amdgcn_cvt_pk_f32_fp8((int)w8.x, true);
        const f32x2 e2 = __builtin_amdgcn_cvt_pk_f32_fp8((int)w8.y, false);
        const f32x2 e3 = __builtin_amdgcn_cvt_pk_f32_fp8((int)w8.y, true);
        const f16x8 w3v = reinterpret_cast<const f16x8*>(fragW3)[(tile * 2 + c) * 64 + lane];
        const f16x8 pp = w3v * (c ? tv1 : tv0);
        int lo = __builtin_amdgcn_cvt_pk_fp8_f32(e0.x + (float)pp[0], e0.y + (float)pp[1], 0, false);
        lo     = __builtin_amdgcn_cvt_pk_fp8_f32(e1.x + (float)pp[2], e1.y + (float)pp[3], lo, true);
        int hi = __builtin_amdgcn_cvt_pk_fp8_f32(e2.x + (float)pp[4], e2.y + (float)pp[5], 0, false);
        hi     = __builtin_amdgcn_cvt_pk_fp8_f32(e3.x + (float)pp[6], e3.y + (float)pp[7], hi, true);
        Aw[i][c] = __builtin_bit_cast(long long, uint2{(unsigned)lo, (unsigned)hi});
      }
      // c-fold: c[n] = b1[n] + sum_k t[k] D[k][n]
      const f16x8 d0 = reinterpret_cast<const f16x8*>(fragDt)[(tile * 2 + 0) * 64 + lane];
      const f16x8 d1 = reinterpret_cast<const f16x8*>(fragDt)[(tile * 2 + 1) * 64 + lane];
      f32x4 acc = {0.f, 0.f, 0.f, 0.f};
      acc = __builtin_amdgcn_mfma_f32_16x16x32_f16(d0, tv0, acc, 0, 0, 0);
      acc = __builtin_amdgcn_mfma_f32_16x16x32_f16(d1, tv1, acc, 0, 0, 0);
      const int nb = tile * 16 + quad * 4;
      const float4 b1v = *reinterpret_cast<const float4*>(&attn_b1[nb]);
      const float4 w2v = *reinterpret_cast<const float4*>(&attn_w2[nb]);
      cn[i][0] = 256.0f * (b1v.x + acc[0]);
      cn[i][1] = 256.0f * (b1v.y + acc[1]);
      cn[i][2] = 256.0f * (b1v.z + acc[2]);
      cn[i][3] = 256.0f * (b1v.w + acc[3]);
      w2n[i][0] = w2v.x * (1.0f / 256.0f);
      w2n[i][1] = w2v.y * (1.0f / 256.0f);
      w2n[i][2] = w2v.z * (1.0f / 256.0f);
      w2n[i][3] = w2v.w * (1.0f / 256.0f);
    }

    if (p == 0) __syncthreads();   // gather complete before first Hf8 read (uniform)

    #pragma unroll 2
    for (int st = 0; st < MT; ++st) {
      const long long b0 = __builtin_bit_cast(long long, Hf8[(st * 2 + 0) * 64 + lane]);
      const long long b1 = __builtin_bit_cast(long long, Hf8[(st * 2 + 1) * 64 + lane]);
      float lg = 0.f;
      #pragma unroll
      for (int i = 0; i < 2; ++i) {
        f32x4 acc = {cn[i][0], cn[i][1], cn[i][2], cn[i][3]};
        acc = __builtin_amdgcn_mfma_f32_16x16x32_fp8_fp8(Aw[i][0], b0, acc, 0, 0, 0);
        acc = __builtin_amdgcn_mfma_f32_16x16x32_fp8_fp8(Aw[i][1], b1, acc, 0, 0, 0);
        #pragma unroll
        for (int q = 0; q < 4; ++q)
          lg += fmaxf(acc[q], 0.0f) * w2n[i][q];
      }
      lg += __shfl_xor(lg, 16, 64);
      lg += __shfl_xor(lg, 32, 64);
      if (lane < 16) {
        if (p == 0) lpf[wave][st * 16 + lane] = lg;
        else        lpf[wave][st * 16 + lane] += lg;   // same lane as p==0 write: no race
      }
    }
  }
  __syncthreads();

  // ---- phase 4: softmax over SEQ (256 threads, one row) ----
  float v = -INFINITY, e = 0.0f;
  if (tid < SEQ)
    v = lpf[0][tid] + lpf[1][tid] + lpf[2][tid] + lpf[3][tid];
  {
    float mx = v;
    #pragma unroll
    for (int off = 32; off; off >>= 1) mx = fmaxf(mx, __shfl_xor(mx, off, 64));
    if (lane == 0) red[wave] = mx;
  }
  __syncthreads();
  {
    const float mx = fmaxf(fmaxf(red[0], red[1]), fmaxf(red[2], red[3]));
    e = (tid < SEQ) ? expf(v - mx) : 0.0f;
    float ssum = e;
    #pragma unroll
    for (int off = 32; off; off >>= 1) ssum += __shfl_xor(ssum, off, 64);
    if (lane == 0) red[4 + wave] = ssum;
  }
  __syncthreads();
  {
    const float tot = red[4] + red[5] + red[6] + red[7];
    if (tid < SEQP) weights[tid] = (tid < SEQ) ? e / tot : 0.0f;
  }
  __syncthreads();

  // ---- phase 5: weighted interest pooling; wave -> (kc = w&1, g2 = w>>1) ----
  {
    const int kc = wave & 1, g2 = wave >> 1;
    float pk[8];
    #pragma unroll
    for (int j = 0; j < 8; ++j) pk[j] = 0.f;
    #pragma unroll
    for (int st2 = 0; st2 < 7; ++st2) {
      const int st = g2 + 2 * st2;
      if (st < MT) {
        const float wt = weights[st * 16 + m];
        const uint2 hv = Hf8[(st * 2 + kc) * 64 + lane];
        const f32x2 f0 = __builtin_amdgcn_cvt_pk_f32_fp8((int)hv.x, false);
        const f32x2 f1 = __builtin_amdgcn_cvt_pk_f32_fp8((int)hv.x, true);
        const f32x2 f2 = __builtin_amdgcn_cvt_pk_f32_fp8((int)hv.y, false);
        const f32x2 f3 = __builtin_amdgcn_cvt_pk_f32_fp8((int)hv.y, true);
        pk[0] += wt * f0.x;  pk[1] += wt * f0.y;
        pk[2] += wt * f1.x;  pk[3] += wt * f1.y;
        pk[4] += wt * f2.x;  pk[5] += wt * f2.y;
        pk[6] += wt * f3.x;  pk[7] += wt * f3.y;
      }
    }
    #pragma unroll
    for (int j = 0; j < 8; ++j) {
      float p = pk[j];
      p += __shfl_xor(p, 1, 64);
      p += __shfl_xor(p, 2, 64);
      p += __shfl_xor(p, 4, 64);
      p += __shfl_xor(p, 8, 64);
      pk[j] = p;
    }
    if (m == 0) {
      float* ip = &lpf[0][0];              // lpf reused: interest partials (16x-scaled)
      #pragma unroll
      for (int j = 0; j < 8; ++j)
        ip[g2 * 64 + kc * 32 + quad * 8 + j] = pk[j];
    }
  }
  __syncthreads();
  if (tid < EMBED) {
    const float* ip = &lpf[0][0];
    mi16[tid] = (_Float16)((ip[tid] + ip[64 + tid]) * 0.0625f);
  }
  __syncthreads();

  // ---- phase 6: prediction head, f16 MFMA; 4 n-tiles/wave ----
  {
    const f16x8 mb0 = *reinterpret_cast<const f16x8*>(&mi16[quad * 8]);
    const f16x8 mb1 = *reinterpret_cast<const f16x8*>(&mi16[32 + quad * 8]);
    float z = 0.f;
    #pragma unroll
    for (int i = 0; i < 4; ++i) {
      const int tt = wave * 4 + i;
      const f16x8* B2 = reinterpret_cast<const f16x8*>(fragB2) + (tt * 4) * 64 + lane;
      const int nb = tt * 16 + quad * 4;
      const float4 bb = *reinterpret_cast<const float4*>(&mlp_b1[nb]);
      const float4 ww = *reinterpret_cast<const float4*>(&mlp_w2[nb]);
      f32x4 acc = {bb.x, bb.y, bb.z, bb.w};
      acc = __builtin_amdgcn_mfma_f32_16x16x32_f16(B2[0],   mb0, acc, 0, 0, 0);
      acc = __builtin_amdgcn_mfma_f32_16x16x32_f16(B2[64],  mb1, acc, 0, 0, 0);
      acc = __builtin_amdgcn_mfma_f32_16x16x32_f16(B2[128], tv0, acc, 0, 0, 0);
      acc = __builtin_amdgcn_mfma_f32_16x16x32_f16(B2[192], tv1, acc, 0, 0, 0);
      z += fmaxf(acc[0], 0.0f) * ww.x;
      z += fmaxf(acc[1], 0.0f) * ww.y;
      z += fmaxf(acc[2], 0.0f) * ww.z;
      z += fmaxf(acc[3], 0.0f) * ww.w;
    }
    z += __shfl_xor(z, 16, 64);
    z += __shfl_xor(z, 32, 64);
    if (lane == 0) red[wave] = z;
  }
  __syncthreads();
  if (tid == 0) {
    const float zz = red[0] + red[1] + red[2] + red[3] + mlp_b2[0];
    out[b] = 1.0f / (1.0f + expf(-zz));
  }
}

extern "C" void kernel_launch(void* const* d_in, const int* in_sizes, int n_in,
                              void* d_out, int out_size, void* d_ws, size_t ws_size,
                              hipStream_t stream) {
  const int*   user_hist   = (const int*)  d_in[0];
  const int*   target_item = (const int*)  d_in[1];
  const float* user_emb    = (const float*)d_in[2];
  const float* item_emb    = (const float*)d_in[3];
  const float* attn_w1     = (const float*)d_in[4];
  const float* attn_b1     = (const float*)d_in[5];
  const float* attn_w2     = (const float*)d_in[6];
  // d_in[7] = attn_b2: constant shift on logits -> cancels in softmax
  const float* mlp_w1      = (const float*)d_in[8];
  const float* mlp_b1      = (const float*)d_in[9];
  const float* mlp_w2      = (const float*)d_in[10];
  const float* mlp_b2      = (const float*)d_in[11];
  float* out = (float*)d_out;

  uint2*    fragB8 = (uint2*)d_ws;                           // 16 KB
  _Float16* fragW3 = (_Float16*)((char*)d_ws + 16384);       // 32 KB
  _Float16* fragDt = (_Float16*)((char*)d_ws + 49152);       // 32 KB
  _Float16* fragB2 = (_Float16*)((char*)d_ws + 81920);       // 64 KB
  const size_t emb8_off = 147456;
  const size_t emb8_bytes = (size_t)VOCAB * EMBED;           // 6.4 MB
  unsigned char* emb8 = nullptr;
  if (ws_size >= emb8_off + emb8_bytes)                      // ws_size is call-invariant: capture-safe
    emb8 = (unsigned char*)d_ws + emb8_off;

  // one setup launch: frag packing (gids 0..10239) + emb8 conversion (rest)
  const int setup_gids = 10240 + VOCAB * EMBED / 8;          // 110240
  din_setup<<<(setup_gids + 255) / 256, 256, 0, stream>>>(
      attn_w1, mlp_w1, user_emb, fragB8, fragW3, fragDt, fragB2,
      emb8 ? emb8 : (unsigned char*)d_ws, emb8 ? 1 : 0);

  const int batch = in_sizes[1];
  din_fused_kernel<<<batch, 256, 0, stream>>>(
      user_hist, target_item, user_emb, item_emb,
      attn_b1, attn_w2, mlp_b1, mlp_w2, mlp_b2,
      fragB8, fragW3, fragDt, fragB2, emb8, out);
}